// Round 1
// baseline (297.722 us; speedup 1.0000x reference)
//
#include <hip/hip_runtime.h>
#include <math.h>

// Problem constants
#define NB 256   // batches
#define NN 32    // agents
#define DD 128   // state dim
#define NA 16    // action dim
#define EE 128   // embed
#define FD 128   // final in
#define HH 256   // hidden

static __device__ __forceinline__ float4 ld4(const float* p){ return *reinterpret_cast<const float4*>(p); }
static __device__ __forceinline__ void st4f(float* p, float4 v){ *reinterpret_cast<float4*>(p) = v; }

// Computes 4x4 outputs per thread of Y[32][*] = X[32][K] @ W[K][*]
// q = t>>5 (row base), c0 = (t&31)*4 (col base). Rows handled: q, q+8, q+16, q+24.
template<int K>
static __device__ __forceinline__ void gemm_acc(const float* __restrict__ X, int ldx,
                                                const float* __restrict__ W, int ldw,
                                                float acc[4][4], int q, int c0)
{
    #pragma unroll 2
    for (int k = 0; k < K; k += 4) {
        float4 xv[4];
        #pragma unroll
        for (int u = 0; u < 4; u++) xv[u] = ld4(X + (q + 8*u)*ldx + k);
        #pragma unroll
        for (int kk = 0; kk < 4; kk++) {
            float4 wv = ld4(W + (k + kk)*ldw + c0);
            #pragma unroll
            for (int u = 0; u < 4; u++) {
                float x = (kk==0) ? xv[u].x : (kk==1) ? xv[u].y : (kk==2) ? xv[u].z : xv[u].w;
                acc[u][0] = fmaf(x, wv.x, acc[u][0]);
                acc[u][1] = fmaf(x, wv.y, acc[u][1]);
                acc[u][2] = fmaf(x, wv.z, acc[u][2]);
                acc[u][3] = fmaf(x, wv.w, acc[u][3]);
            }
        }
    }
}

static __device__ __forceinline__ void zero_acc(float acc[4][4]){
    #pragma unroll
    for (int u=0;u<4;u++){
        #pragma unroll
        for (int c=0;c<4;c++) acc[u][c]=0.f;
    }
}

static __device__ __forceinline__ void store_acc(float* __restrict__ Y, int ldy,
                                                 float acc[4][4], int q, int c0){
    #pragma unroll
    for (int u=0;u<4;u++)
        st4f(Y + (q + 8*u)*ldy + c0, make_float4(acc[u][0],acc[u][1],acc[u][2],acc[u][3]));
}

// scores = Q(32x128) . Kt(32x128)^T * scale, row-softmax; writes result to
// w_lds (leading dim 36) and w_out (global, 32x32). Contains one internal sync.
static __device__ __forceinline__ void scores_softmax(const float* __restrict__ Q,
                                                      const float* __restrict__ Kt,
                                                      float scale,
                                                      float* __restrict__ w_lds,
                                                      float* __restrict__ w_out,
                                                      int t)
{
    int i  = t >> 3;
    int j0 = (t & 7) * 4;
    float s[4] = {0.f,0.f,0.f,0.f};
    #pragma unroll 4
    for (int k = 0; k < 128; k += 4) {
        float4 qv = ld4(Q + i*128 + k);
        #pragma unroll
        for (int jj = 0; jj < 4; jj++) {
            float4 kv = ld4(Kt + (j0+jj)*128 + k);
            s[jj] += qv.x*kv.x + qv.y*kv.y + qv.z*kv.z + qv.w*kv.w;
        }
    }
    #pragma unroll
    for (int jj = 0; jj < 4; jj++) s[jj] *= scale;
    __syncthreads();   // all reads of Q/Kt done; safe to overwrite their buffers
    float m = fmaxf(fmaxf(s[0],s[1]), fmaxf(s[2],s[3]));
    #pragma unroll
    for (int d = 1; d < 8; d <<= 1) m = fmaxf(m, __shfl_xor(m, d));
    float e[4], sum = 0.f;
    #pragma unroll
    for (int jj = 0; jj < 4; jj++) { e[jj] = expf(s[jj] - m); sum += e[jj]; }
    #pragma unroll
    for (int d = 1; d < 8; d <<= 1) sum += __shfl_xor(sum, d);
    float inv = 1.f / sum;
    #pragma unroll
    for (int jj = 0; jj < 4; jj++) {
        float w = e[jj] * inv;
        w_lds[i*36 + j0 + jj] = w;
        w_out[i*32 + j0 + jj] = w;
    }
}

// Kernel 1: per-batch attention stages + S / diff precompute.
__global__ __launch_bounds__(256)
void k_attn(const float* __restrict__ states, const float* __restrict__ pol,
            const float* __restrict__ act,
            const float* __restrict__ Wkp, const float* __restrict__ Wqp,
            const float* __restrict__ Wvp, const float* __restrict__ Wk,
            const float* __restrict__ Wq,  const float* __restrict__ We,
            const float* __restrict__ Wav,
            float* __restrict__ out_w1, float* __restrict__ out_w2,
            float* __restrict__ wsS, float* __restrict__ wsD)
{
    const int b = blockIdx.x;
    const int t = threadIdx.x;
    const float scale = 0.08838834764831845f;  // 1/sqrt(128)

    __shared__ float lds[4*4096];
    float* st = lds;
    float* bA = lds + 4096;
    float* bB = lds + 2*4096;
    float* bC = lds + 3*4096;

    // load states[b] (32x128)
    const float* stg = states + (size_t)b * (NN*DD);
    #pragma unroll
    for (int u = 0; u < 4; u++) { int i4 = t + 256*u; st4f(st + i4*4, ld4(stg + i4*4)); }
    __syncthreads();

    const int q  = t >> 5;
    const int c0 = (t & 31) * 4;
    float acc[4][4];

    // q1 -> bA, k1 -> bB, v1 -> bC
    zero_acc(acc); gemm_acc<128>(st, 128, Wqp, 128, acc, q, c0); store_acc(bA, 128, acc, q, c0);
    zero_acc(acc); gemm_acc<128>(st, 128, Wkp, 128, acc, q, c0); store_acc(bB, 128, acc, q, c0);
    zero_acc(acc); gemm_acc<128>(st, 128, Wvp, 128, acc, q, c0); store_acc(bC, 128, acc, q, c0);
    __syncthreads();

    // w1 = softmax(q1.k1^T * scale) -> bA (ld 36) + out
    scores_softmax(bA, bB, scale, bA, out_w1 + (size_t)b*1024, t);
    __syncthreads();

    // wav1 = w1 @ v1 -> bB
    zero_acc(acc); gemm_acc<32>(bA, 36, bC, 128, acc, q, c0); store_acc(bB, 128, acc, q, c0);
    __syncthreads();

    // k2 -> bC, q2 -> bA
    zero_acc(acc); gemm_acc<128>(bB, 128, Wk, 128, acc, q, c0); store_acc(bC, 128, acc, q, c0);
    zero_acc(acc); gemm_acc<128>(bB, 128, Wq, 128, acc, q, c0); store_acc(bA, 128, acc, q, c0);
    __syncthreads();

    // w2 = softmax(q2.k2^T * scale) -> bB (ld 36) + out
    scores_softmax(bA, bC, scale, bB, out_w2 + (size_t)b*1024, t);
    __syncthreads();

    // e_oa = [states|actions] @ We -> bA
    const float* actb = act + (size_t)b * (NN*NA);
    const float* polb = pol + (size_t)b * (NN*NA);
    zero_acc(acc);
    gemm_acc<128>(st, 128, We, 128, acc, q, c0);
    #pragma unroll
    for (int kk = 0; kk < 16; kk++) {
        float4 wv = ld4(We + (128 + kk)*128 + c0);
        #pragma unroll
        for (int u = 0; u < 4; u++) {
            float x = actb[(q + 8*u)*NA + kk];
            acc[u][0] = fmaf(x, wv.x, acc[u][0]);
            acc[u][1] = fmaf(x, wv.y, acc[u][1]);
            acc[u][2] = fmaf(x, wv.z, acc[u][2]);
            acc[u][3] = fmaf(x, wv.w, acc[u][3]);
        }
    }
    store_acc(bA, 128, acc, q, c0);

    // e_diff = (pol-act) @ We[128:144] -> bC
    zero_acc(acc);
    #pragma unroll
    for (int kk = 0; kk < 16; kk++) {
        float4 wv = ld4(We + (128 + kk)*128 + c0);
        #pragma unroll
        for (int u = 0; u < 4; u++) {
            float x = polb[(q + 8*u)*NA + kk] - actb[(q + 8*u)*NA + kk];
            acc[u][0] = fmaf(x, wv.x, acc[u][0]);
            acc[u][1] = fmaf(x, wv.y, acc[u][1]);
            acc[u][2] = fmaf(x, wv.z, acc[u][2]);
            acc[u][3] = fmaf(x, wv.w, acc[u][3]);
        }
    }
    store_acc(bC, 128, acc, q, c0);
    __syncthreads();

    // av_oa = e_oa @ Wav -> st (states no longer needed)
    zero_acc(acc); gemm_acc<128>(bA, 128, Wav, 128, acc, q, c0); store_acc(st, 128, acc, q, c0);
    __syncthreads();

    // diff = e_diff @ Wav -> ws
    zero_acc(acc); gemm_acc<128>(bC, 128, Wav, 128, acc, q, c0);
    store_acc(wsD + (size_t)b*4096, 128, acc, q, c0);

    // S = w2 @ av_oa -> ws
    zero_acc(acc); gemm_acc<32>(bB, 36, st, 128, acc, q, c0);
    store_acc(wsS + (size_t)b*4096, 128, acc, q, c0);
}

// Kernel 2: value[b,i,j] = leaky(node @ W1) @ W2 with
// node[b,i,j,:] = S[b,i,:] + w2[b,i,j]*diff[b,j,:]
// Block handles (b, 2 i's x 32 j's) = 64 pairs x 256 h.
__global__ __launch_bounds__(256)
void k_value(const float* __restrict__ wsS, const float* __restrict__ wsD,
             const float* __restrict__ w2g, const float* __restrict__ W1,
             const float* __restrict__ W2, float* __restrict__ out_v)
{
    const int blk = blockIdx.x;
    const int b  = blk >> 4;
    const int mt = blk & 15;   // i-tile: rows 2*mt, 2*mt+1
    const int t  = threadIdx.x;
    const int ty = t >> 5;     // 0..7  -> rows ty*8..ty*8+7 of the 64-pair tile
    const int tx = t & 31;     // h = tx + 32*hh

    __shared__ float diffs[32*130];   // diff[b][j][:], ld 130 (bank-conflict pad)
    __shared__ float S2[2*128];
    __shared__ float w2t[64];         // w2[b][2mt..2mt+1][0..31]
    __shared__ float W1c[16*256];     // W1 k-chunk
    __shared__ float nodec[16*64];    // node chunk, [kk][pair]

    // stage diffs (padded rows), S2, w2t
    {
        const float* src = wsD + (size_t)b*4096;
        #pragma unroll
        for (int u = 0; u < 4; u++) {
            int f4 = t + 256*u;          // float4 index 0..1023
            int j  = f4 >> 5;            // row
            int c4 = f4 & 31;            // float4 within row
            st4f(diffs + j*130 + c4*4, ld4(src + f4*4));
        }
        S2[t] = wsS[(size_t)b*4096 + (2*mt)*128 + t];
        if (t < 64) w2t[t] = w2g[(size_t)b*1024 + (2*mt)*32 + t];
    }

    float accv[8][8];
    #pragma unroll
    for (int r = 0; r < 8; r++){
        #pragma unroll
        for (int h = 0; h < 8; h++) accv[r][h] = 0.f;
    }

    for (int k0 = 0; k0 < 128; k0 += 16) {
        __syncthreads();  // protect previous chunk reads (and initial staging)
        // stage W1 chunk [16][256]
        #pragma unroll
        for (int u = 0; u < 4; u++) {
            int f4 = t + 256*u;
            st4f(W1c + f4*4, ld4(W1 + k0*256 + f4*4));
        }
        // generate node chunk: nodec[kk][p]
        #pragma unroll
        for (int u = 0; u < 4; u++) {
            int idx = t + 256*u;
            int kk  = idx >> 6;
            int p   = idx & 63;
            int il  = p >> 5;
            int j   = p & 31;
            nodec[idx /* kk*64+p */] = S2[il*128 + k0 + kk] + w2t[il*32 + j] * diffs[j*130 + k0 + kk];
        }
        __syncthreads();

        #pragma unroll 8
        for (int kk = 0; kk < 16; kk++) {
            float a[8];
            float4 a0 = ld4(nodec + kk*64 + ty*8);
            float4 a1 = ld4(nodec + kk*64 + ty*8 + 4);
            a[0]=a0.x; a[1]=a0.y; a[2]=a0.z; a[3]=a0.w;
            a[4]=a1.x; a[5]=a1.y; a[6]=a1.z; a[7]=a1.w;
            float bv[8];
            #pragma unroll
            for (int hh = 0; hh < 8; hh++) bv[hh] = W1c[kk*256 + tx + 32*hh];
            #pragma unroll
            for (int r = 0; r < 8; r++){
                #pragma unroll
                for (int hh = 0; hh < 8; hh++)
                    accv[r][hh] = fmaf(a[r], bv[hh], accv[r][hh]);
            }
        }
    }

    // epilogue: leaky relu, * W2, reduce over h (across the 32 tx lanes)
    float w2h[8];
    #pragma unroll
    for (int hh = 0; hh < 8; hh++) w2h[hh] = W2[tx + 32*hh];

    #pragma unroll
    for (int r = 0; r < 8; r++) {
        float partial = 0.f;
        #pragma unroll
        for (int hh = 0; hh < 8; hh++) {
            float x = accv[r][hh];
            x = (x > 0.f) ? x : 0.01f * x;
            partial = fmaf(x, w2h[hh], partial);
        }
        #pragma unroll
        for (int d = 1; d < 32; d <<= 1) partial += __shfl_xor(partial, d);
        if (tx == 0)
            out_v[(size_t)b*1024 + mt*64 + ty*8 + r] = partial;
    }
}

extern "C" void kernel_launch(void* const* d_in, const int* in_sizes, int n_in,
                              void* d_out, int out_size, void* d_ws, size_t ws_size,
                              hipStream_t stream) {
    const float* states = (const float*)d_in[0];
    const float* pol    = (const float*)d_in[1];
    const float* act    = (const float*)d_in[2];
    const float* Wkp    = (const float*)d_in[3];
    const float* Wqp    = (const float*)d_in[4];
    const float* Wvp    = (const float*)d_in[5];
    const float* Wk     = (const float*)d_in[6];
    const float* Wq     = (const float*)d_in[7];
    const float* We     = (const float*)d_in[8];
    const float* Wav    = (const float*)d_in[9];
    const float* W1     = (const float*)d_in[10];
    const float* W2     = (const float*)d_in[11];

    float* out    = (float*)d_out;
    float* out_v  = out;                 // [256,32,32,1]
    float* out_w1 = out + 256*1024;      // [256,32,32]
    float* out_w2 = out + 2*256*1024;    // [256,32,32]

    float* wsS = (float*)d_ws;           // [256][32][128]
    float* wsD = wsS + 256*32*128;       // [256][32][128]

    hipLaunchKernelGGL(k_attn, dim3(NB), dim3(256), 0, stream,
                       states, pol, act, Wkp, Wqp, Wvp, Wk, Wq, We, Wav,
                       out_w1, out_w2, wsS, wsD);
    hipLaunchKernelGGL(k_value, dim3(NB*16), dim3(256), 0, stream,
                       wsS, wsD, out_w2, W1, W2, out_v);
}

// Round 2
// 90.791 us; speedup vs baseline: 3.2792x; 3.2792x over previous
//
#include <hip/hip_runtime.h>
#include <math.h>

// Problem constants
#define NB 256   // batches
#define NN 32    // agents
#define DD 128   // state dim
#define NA 16    // action dim
#define EE 128   // embed
#define FD 128   // final in
#define HH 256   // hidden

static __device__ __forceinline__ float4 ld4(const float* p){ return *reinterpret_cast<const float4*>(p); }
static __device__ __forceinline__ void st4f(float* p, float4 v){ *reinterpret_cast<float4*>(p) = v; }

static __device__ __forceinline__ unsigned short f2bf(float x){
    unsigned int u = __float_as_uint(x);
    u += 0x7fffu + ((u >> 16) & 1u);   // round-to-nearest-even
    return (unsigned short)(u >> 16);
}

// Computes 4x4 outputs per thread of Y[32][*] = X[32][K] @ W[K][*]
// q = t>>5 (row base), c0 = (t&31)*4 (col base). Rows handled: q, q+8, q+16, q+24.
template<int K>
static __device__ __forceinline__ void gemm_acc(const float* __restrict__ X, int ldx,
                                                const float* __restrict__ W, int ldw,
                                                float acc[4][4], int q, int c0)
{
    #pragma unroll 2
    for (int k = 0; k < K; k += 4) {
        float4 xv[4];
        #pragma unroll
        for (int u = 0; u < 4; u++) xv[u] = ld4(X + (q + 8*u)*ldx + k);
        #pragma unroll
        for (int kk = 0; kk < 4; kk++) {
            float4 wv = ld4(W + (k + kk)*ldw + c0);
            #pragma unroll
            for (int u = 0; u < 4; u++) {
                float x = (kk==0) ? xv[u].x : (kk==1) ? xv[u].y : (kk==2) ? xv[u].z : xv[u].w;
                acc[u][0] = fmaf(x, wv.x, acc[u][0]);
                acc[u][1] = fmaf(x, wv.y, acc[u][1]);
                acc[u][2] = fmaf(x, wv.z, acc[u][2]);
                acc[u][3] = fmaf(x, wv.w, acc[u][3]);
            }
        }
    }
}

static __device__ __forceinline__ void zero_acc(float acc[4][4]){
    #pragma unroll
    for (int u=0;u<4;u++){
        #pragma unroll
        for (int c=0;c<4;c++) acc[u][c]=0.f;
    }
}

static __device__ __forceinline__ void store_acc(float* __restrict__ Y, int ldy,
                                                 float acc[4][4], int q, int c0){
    #pragma unroll
    for (int u=0;u<4;u++)
        st4f(Y + (q + 8*u)*ldy + c0, make_float4(acc[u][0],acc[u][1],acc[u][2],acc[u][3]));
}

static __device__ __forceinline__ void store_acc_bf16(unsigned short* __restrict__ Y, int ldy,
                                                      float acc[4][4], int q, int c0){
    #pragma unroll
    for (int u=0;u<4;u++){
        ushort4 v;
        v.x = f2bf(acc[u][0]); v.y = f2bf(acc[u][1]);
        v.z = f2bf(acc[u][2]); v.w = f2bf(acc[u][3]);
        *reinterpret_cast<ushort4*>(Y + (q + 8*u)*ldy + c0) = v;
    }
}

// scores = Q(32x128) . Kt(32x128)^T * scale, row-softmax; writes result to
// w_lds (leading dim 36) and w_out (global, 32x32). Contains one internal sync.
static __device__ __forceinline__ void scores_softmax(const float* __restrict__ Q,
                                                      const float* __restrict__ Kt,
                                                      float scale,
                                                      float* __restrict__ w_lds,
                                                      float* __restrict__ w_out,
                                                      int t)
{
    int i  = t >> 3;
    int j0 = (t & 7) * 4;
    float s[4] = {0.f,0.f,0.f,0.f};
    #pragma unroll 4
    for (int k = 0; k < 128; k += 4) {
        float4 qv = ld4(Q + i*128 + k);
        #pragma unroll
        for (int jj = 0; jj < 4; jj++) {
            float4 kv = ld4(Kt + (j0+jj)*128 + k);
            s[jj] += qv.x*kv.x + qv.y*kv.y + qv.z*kv.z + qv.w*kv.w;
        }
    }
    #pragma unroll
    for (int jj = 0; jj < 4; jj++) s[jj] *= scale;
    __syncthreads();   // all reads of Q/Kt done; safe to overwrite their buffers
    float m = fmaxf(fmaxf(s[0],s[1]), fmaxf(s[2],s[3]));
    #pragma unroll
    for (int d = 1; d < 8; d <<= 1) m = fmaxf(m, __shfl_xor(m, d));
    float e[4], sum = 0.f;
    #pragma unroll
    for (int jj = 0; jj < 4; jj++) { e[jj] = expf(s[jj] - m); sum += e[jj]; }
    #pragma unroll
    for (int d = 1; d < 8; d <<= 1) sum += __shfl_xor(sum, d);
    float inv = 1.f / sum;
    #pragma unroll
    for (int jj = 0; jj < 4; jj++) {
        float w = e[jj] * inv;
        w_lds[i*36 + j0 + jj] = w;
        w_out[i*32 + j0 + jj] = w;
    }
}

// Kernel 1: per-batch attention stages + P/Q precompute.
// P = (w2 @ av_oa) @ W1   [32][256]  (bf16 out)
// Q = diff @ W1           [32][256]  (bf16 out)
__global__ __launch_bounds__(256)
void k_attn(const float* __restrict__ states, const float* __restrict__ pol,
            const float* __restrict__ act,
            const float* __restrict__ Wkp, const float* __restrict__ Wqp,
            const float* __restrict__ Wvp, const float* __restrict__ Wk,
            const float* __restrict__ Wq,  const float* __restrict__ We,
            const float* __restrict__ Wav, const float* __restrict__ W1,
            float* __restrict__ out_w1, float* __restrict__ out_w2,
            unsigned short* __restrict__ wsP, unsigned short* __restrict__ wsQ)
{
    const int b = blockIdx.x;
    const int t = threadIdx.x;
    const float scale = 0.08838834764831845f;  // 1/sqrt(128)

    __shared__ float lds[4*4096];
    float* st = lds;
    float* bA = lds + 4096;
    float* bB = lds + 2*4096;
    float* bC = lds + 3*4096;

    // load states[b] (32x128)
    const float* stg = states + (size_t)b * (NN*DD);
    #pragma unroll
    for (int u = 0; u < 4; u++) { int i4 = t + 256*u; st4f(st + i4*4, ld4(stg + i4*4)); }
    __syncthreads();

    const int q  = t >> 5;
    const int c0 = (t & 31) * 4;
    float acc[4][4];

    // q1 -> bA, k1 -> bB, v1 -> bC
    zero_acc(acc); gemm_acc<128>(st, 128, Wqp, 128, acc, q, c0); store_acc(bA, 128, acc, q, c0);
    zero_acc(acc); gemm_acc<128>(st, 128, Wkp, 128, acc, q, c0); store_acc(bB, 128, acc, q, c0);
    zero_acc(acc); gemm_acc<128>(st, 128, Wvp, 128, acc, q, c0); store_acc(bC, 128, acc, q, c0);
    __syncthreads();

    // w1 = softmax(q1.k1^T * scale) -> bA (ld 36) + out
    scores_softmax(bA, bB, scale, bA, out_w1 + (size_t)b*1024, t);
    __syncthreads();

    // wav1 = w1 @ v1 -> bB
    zero_acc(acc); gemm_acc<32>(bA, 36, bC, 128, acc, q, c0); store_acc(bB, 128, acc, q, c0);
    __syncthreads();

    // k2 -> bC, q2 -> bA
    zero_acc(acc); gemm_acc<128>(bB, 128, Wk, 128, acc, q, c0); store_acc(bC, 128, acc, q, c0);
    zero_acc(acc); gemm_acc<128>(bB, 128, Wq, 128, acc, q, c0); store_acc(bA, 128, acc, q, c0);
    __syncthreads();

    // w2 = softmax(q2.k2^T * scale) -> bB (ld 36) + out
    scores_softmax(bA, bC, scale, bB, out_w2 + (size_t)b*1024, t);
    __syncthreads();

    // e_oa = [states|actions] @ We -> bA
    const float* actb = act + (size_t)b * (NN*NA);
    const float* polb = pol + (size_t)b * (NN*NA);
    zero_acc(acc);
    gemm_acc<128>(st, 128, We, 128, acc, q, c0);
    #pragma unroll
    for (int kk = 0; kk < 16; kk++) {
        float4 wv = ld4(We + (128 + kk)*128 + c0);
        #pragma unroll
        for (int u = 0; u < 4; u++) {
            float x = actb[(q + 8*u)*NA + kk];
            acc[u][0] = fmaf(x, wv.x, acc[u][0]);
            acc[u][1] = fmaf(x, wv.y, acc[u][1]);
            acc[u][2] = fmaf(x, wv.z, acc[u][2]);
            acc[u][3] = fmaf(x, wv.w, acc[u][3]);
        }
    }
    store_acc(bA, 128, acc, q, c0);

    // e_diff = (pol-act) @ We[128:144] -> bC
    zero_acc(acc);
    #pragma unroll
    for (int kk = 0; kk < 16; kk++) {
        float4 wv = ld4(We + (128 + kk)*128 + c0);
        #pragma unroll
        for (int u = 0; u < 4; u++) {
            float x = polb[(q + 8*u)*NA + kk] - actb[(q + 8*u)*NA + kk];
            acc[u][0] = fmaf(x, wv.x, acc[u][0]);
            acc[u][1] = fmaf(x, wv.y, acc[u][1]);
            acc[u][2] = fmaf(x, wv.z, acc[u][2]);
            acc[u][3] = fmaf(x, wv.w, acc[u][3]);
        }
    }
    store_acc(bC, 128, acc, q, c0);
    __syncthreads();

    // av_oa = e_oa @ Wav -> st (states no longer needed)
    zero_acc(acc); gemm_acc<128>(bA, 128, Wav, 128, acc, q, c0); store_acc(st, 128, acc, q, c0);
    __syncthreads();

    // diff = e_diff @ Wav (regs) ; S = w2 @ av_oa (regs)
    float accD[4][4], accS[4][4];
    zero_acc(accD); gemm_acc<128>(bC, 128, Wav, 128, accD, q, c0);
    zero_acc(accS); gemm_acc<32>(bB, 36, st, 128, accS, q, c0);
    __syncthreads();                    // all reads of bA/bC/st/bB complete
    store_acc(bA, 128, accD, q, c0);    // diff -> bA
    store_acc(bC, 128, accS, q, c0);    // S    -> bC
    __syncthreads();

    // Q = diff @ W1 -> wsQ (bf16) ; P = S @ W1 -> wsP (bf16). W1 is [128][256].
    unsigned short* pP = wsP + (size_t)b * (NN*HH);
    unsigned short* pQ = wsQ + (size_t)b * (NN*HH);
    zero_acc(acc); gemm_acc<128>(bA, 128, W1,       256, acc, q, c0); store_acc_bf16(pQ,       256, acc, q, c0);
    zero_acc(acc); gemm_acc<128>(bA, 128, W1 + 128, 256, acc, q, c0); store_acc_bf16(pQ + 128, 256, acc, q, c0);
    zero_acc(acc); gemm_acc<128>(bC, 128, W1,       256, acc, q, c0); store_acc_bf16(pP,       256, acc, q, c0);
    zero_acc(acc); gemm_acc<128>(bC, 128, W1 + 128, 256, acc, q, c0); store_acc_bf16(pP + 128, 256, acc, q, c0);
}

// Kernel 2 (factored): value[b,i,j] = sum_h W2[h] * leaky(P[b,i,h] + w2[b,i,j]*Q[b,j,h])
// One block per batch; thread t covers the 2x2 tile {i0,i0+16} x {j0,j0+16}.
__global__ __launch_bounds__(256)
void k_value(const unsigned short* __restrict__ wsP, const unsigned short* __restrict__ wsQ,
             const float* __restrict__ w2g, const float* __restrict__ W2,
             float* __restrict__ out_v)
{
    const int b  = blockIdx.x;
    const int t  = threadIdx.x;
    const int i0 = t >> 4;   // 0..15
    const int j0 = t & 15;   // 0..15

    __shared__ unsigned int P2[32*132];  // packed bf16 pairs, padded rows (16B-aligned stores)
    __shared__ unsigned int Q2[32*132];
    __shared__ float W2s[256];

    // stage P,Q: each is 32x256 ushort = 1024 uint4 loads
    const uint4* srcP = reinterpret_cast<const uint4*>(wsP + (size_t)b * (NN*HH));
    const uint4* srcQ = reinterpret_cast<const uint4*>(wsQ + (size_t)b * (NN*HH));
    #pragma unroll
    for (int u = 0; u < 4; u++) {
        int idx = t + 256*u;       // uint4 index 0..1023
        int row = idx >> 5;        // 32 uint4 per row
        int c4  = idx & 31;
        *reinterpret_cast<uint4*>(P2 + row*132 + c4*4) = srcP[idx];
        *reinterpret_cast<uint4*>(Q2 + row*132 + c4*4) = srcQ[idx];
    }
    W2s[t] = W2[t];

    const float* w2b = w2g + (size_t)b * 1024;
    const float w00 = w2b[ i0      *32 + j0     ];
    const float w01 = w2b[ i0      *32 + j0 + 16];
    const float w10 = w2b[(i0 + 16)*32 + j0     ];
    const float w11 = w2b[(i0 + 16)*32 + j0 + 16];
    __syncthreads();

    float a00 = 0.f, a01 = 0.f, a10 = 0.f, a11 = 0.f;

    #pragma unroll 8
    for (int hp = 0; hp < 128; hp++) {
        unsigned int pa = P2[ i0      *132 + hp];
        unsigned int pb = P2[(i0 + 16)*132 + hp];
        unsigned int qa = Q2[ j0      *132 + hp];
        unsigned int qb = Q2[(j0 + 16)*132 + hp];
        float w2e = W2s[2*hp], w2o = W2s[2*hp + 1];

        float paE = __uint_as_float(pa << 16), paO = __uint_as_float(pa & 0xffff0000u);
        float pbE = __uint_as_float(pb << 16), pbO = __uint_as_float(pb & 0xffff0000u);
        float qaE = __uint_as_float(qa << 16), qaO = __uint_as_float(qa & 0xffff0000u);
        float qbE = __uint_as_float(qb << 16), qbO = __uint_as_float(qb & 0xffff0000u);

        // leaky(x) = 0.505x + 0.495|x|  (exact for slope 0.01; |x| folds to operand modifier)
        #define STEP(P_, Q_, W_, W2H, ACC) {                        \
            float t_ = fmaf((W_), (Q_), (P_));                      \
            float u_ = fmaf(0.495f, fabsf(t_), 0.505f * t_);        \
            (ACC) = fmaf(u_, (W2H), (ACC)); }

        STEP(paE, qaE, w00, w2e, a00)  STEP(paO, qaO, w00, w2o, a00)
        STEP(paE, qbE, w01, w2e, a01)  STEP(paO, qbO, w01, w2o, a01)
        STEP(pbE, qaE, w10, w2e, a10)  STEP(pbO, qaO, w10, w2o, a10)
        STEP(pbE, qbE, w11, w2e, a11)  STEP(pbO, qbO, w11, w2o, a11)
        #undef STEP
    }

    float* ov = out_v + (size_t)b * 1024;
    ov[ i0      *32 + j0     ] = a00;
    ov[ i0      *32 + j0 + 16] = a01;
    ov[(i0 + 16)*32 + j0     ] = a10;
    ov[(i0 + 16)*32 + j0 + 16] = a11;
}

extern "C" void kernel_launch(void* const* d_in, const int* in_sizes, int n_in,
                              void* d_out, int out_size, void* d_ws, size_t ws_size,
                              hipStream_t stream) {
    const float* states = (const float*)d_in[0];
    const float* pol    = (const float*)d_in[1];
    const float* act    = (const float*)d_in[2];
    const float* Wkp    = (const float*)d_in[3];
    const float* Wqp    = (const float*)d_in[4];
    const float* Wvp    = (const float*)d_in[5];
    const float* Wk     = (const float*)d_in[6];
    const float* Wq     = (const float*)d_in[7];
    const float* We     = (const float*)d_in[8];
    const float* Wav    = (const float*)d_in[9];
    const float* W1     = (const float*)d_in[10];
    const float* W2     = (const float*)d_in[11];

    float* out    = (float*)d_out;
    float* out_v  = out;                 // [256,32,32,1]
    float* out_w1 = out + 256*1024;      // [256,32,32]
    float* out_w2 = out + 2*256*1024;    // [256,32,32]

    unsigned short* wsP = (unsigned short*)d_ws;     // [256][32][256] bf16
    unsigned short* wsQ = wsP + (size_t)256*32*256;  // [256][32][256] bf16

    hipLaunchKernelGGL(k_attn, dim3(NB), dim3(256), 0, stream,
                       states, pol, act, Wkp, Wqp, Wvp, Wk, Wq, We, Wav, W1,
                       out_w1, out_w2, wsP, wsQ);
    hipLaunchKernelGGL(k_value, dim3(NB), dim3(256), 0, stream,
                       wsP, wsQ, out_w2, W2, out_v);
}